// Round 1
// baseline (2818.269 us; speedup 1.0000x reference)
//
#include <hip/hip_runtime.h>
#include <math.h>

// Problem constants (from reference): B,S,H,HKV,D = 2,2048,32,8,128
#define B_    2
#define S_    2048
#define H_    32
#define HKV_  8
#define D_    128
#define REP_  (H_ / HKV_)                 // 4
#define SCALE 0.08838834764831845f        // 1/sqrt(128)

#define KV_ROW (HKV_ * D_)                // 1024 floats per cache row
#define NSLOT  (B_ * S_)                  // 4096
#define OUT_OFF_K ((size_t)B_ * S_ * H_ * D_)   // 16777216 floats

// Flash-attention tiling
#define BR 32          // query rows per block
#define BC 64          // keys per tile
#define QT_LD (BR + 4) // 36, transposed q leading dim (float4-aligned)
#define KT_LD (BC + 4) // 68, transposed k leading dim
#define VT_LD (D_ + 4) // 132, v leading dim
#define PS_LD (BC + 1) // 65, score tile leading dim

// ---------------------------------------------------------------------------
// Cache copy: out caches must start as the input caches (slots not in the
// mapping keep their old value; d_out is poisoned before each run).
__global__ void copy_caches_kernel(const float* __restrict__ kc,
                                   const float* __restrict__ vc,
                                   float* __restrict__ out) {
    const int n4 = NSLOT * KV_ROW / 4;  // float4s per cache
    float4* ok = (float4*)(out + OUT_OFF_K);
    float4* ov = (float4*)(out + OUT_OFF_K + (size_t)NSLOT * KV_ROW);
    const float4* ik = (const float4*)kc;
    const float4* iv = (const float4*)vc;
    for (int i = blockIdx.x * blockDim.x + threadIdx.x; i < n4;
         i += gridDim.x * blockDim.x) {
        ok[i] = ik[i];
        ov[i] = iv[i];
    }
}

// Slot-mapped scatter: one block per source row, 256 threads x float4 = 1024 f.
__global__ void scatter_kernel(const float* __restrict__ k,
                               const float* __restrict__ v,
                               const int* __restrict__ slot,
                               float* __restrict__ out) {
    const int row = blockIdx.x;
    const int dst = slot[row];
    const float4* ks = (const float4*)(k + (size_t)row * KV_ROW);
    const float4* vs = (const float4*)(v + (size_t)row * KV_ROW);
    float4* kd = (float4*)(out + OUT_OFF_K + (size_t)dst * KV_ROW);
    float4* vd = (float4*)(out + OUT_OFF_K + (size_t)NSLOT * KV_ROW +
                           (size_t)dst * KV_ROW);
    const int t = threadIdx.x;
    kd[t] = ks[t];
    vd[t] = vs[t];
}

// ---------------------------------------------------------------------------
// Causal GQA flash attention, fp32 VALU version.
// Grid: (S/BR, B*H). Block: 256 threads.
__global__ __launch_bounds__(256, 2) void attn_kernel(
    const float* __restrict__ q, const float* __restrict__ k,
    const float* __restrict__ v, float* __restrict__ out) {
    __shared__ float q_t[D_ * QT_LD];   // q transposed [d][r], pre-scaled
    __shared__ float kv[D_ * KT_LD];    // k transposed [d][j]; aliased v [j][d]
    __shared__ float p_s[BR * PS_LD];   // scores -> probs
    __shared__ float m_s[BR], l_s[BR], al_s[BR];

    const int qt  = blockIdx.x;
    const int bh  = blockIdx.y;
    const int b   = bh / H_;
    const int h   = bh % H_;
    const int hkv = h / REP_;
    const int tid = threadIdx.x;
    const int q0  = qt * BR;

    // ---- stage Q (transposed, scaled) ----
    {
        const float* qbase = q + (((size_t)b * S_ + q0) * H_ + h) * D_;
        for (int i = tid; i < BR * (D_ / 4); i += 256) {
            const int r  = i >> 5;       // row 0..31
            const int c4 = i & 31;       // float4 index along d
            const float4 val =
                *(const float4*)(qbase + (size_t)r * (H_ * D_) + c4 * 4);
            const int d0 = c4 * 4;
            q_t[(d0 + 0) * QT_LD + r] = val.x * SCALE;
            q_t[(d0 + 1) * QT_LD + r] = val.y * SCALE;
            q_t[(d0 + 2) * QT_LD + r] = val.z * SCALE;
            q_t[(d0 + 3) * QT_LD + r] = val.w * SCALE;
        }
    }
    if (tid < BR) { m_s[tid] = -1e30f; l_s[tid] = 0.0f; }

    // PV / output mapping: rows g*4..+3, d columns c*4..+3
    const int g = tid >> 5;   // 0..7
    const int c = tid & 31;   // 0..31
    float acc[4][4];
#pragma unroll
    for (int a = 0; a < 4; ++a)
#pragma unroll
        for (int e = 0; e < 4; ++e) acc[a][e] = 0.0f;

    // score mapping: rows sy*4..+3, cols sx*2, sx*2+1
    const int sy = tid >> 5;
    const int sx = tid & 31;

    const int q_hi = q0 + BR - 1;
    const int nkt  = q_hi / BC + 1;

    const float* kbase = k + (((size_t)b * S_) * HKV_ + hkv) * D_;
    const float* vbase = v + (((size_t)b * S_) * HKV_ + hkv) * D_;

    for (int kt = 0; kt < nkt; ++kt) {
        const int j0 = kt * BC;
        __syncthreads();  // kv buffer free from previous PV
        // ---- stage K transposed ----
        for (int i = tid; i < BC * (D_ / 4); i += 256) {
            const int j  = i >> 5;
            const int c4 = i & 31;
            const float4 val =
                *(const float4*)(kbase + (size_t)(j0 + j) * (HKV_ * D_) + c4 * 4);
            const int d0 = c4 * 4;
            kv[(d0 + 0) * KT_LD + j] = val.x;
            kv[(d0 + 1) * KT_LD + j] = val.y;
            kv[(d0 + 2) * KT_LD + j] = val.z;
            kv[(d0 + 3) * KT_LD + j] = val.w;
        }
        __syncthreads();

        // ---- scores: 4 rows x 2 cols per thread ----
        float sacc[4][2];
#pragma unroll
        for (int a = 0; a < 4; ++a) { sacc[a][0] = 0.f; sacc[a][1] = 0.f; }
#pragma unroll 4
        for (int d = 0; d < D_; ++d) {
            const float4 qv = *(const float4*)&q_t[d * QT_LD + sy * 4];
            const float2 kw = *(const float2*)&kv[d * KT_LD + sx * 2];
            sacc[0][0] += qv.x * kw.x; sacc[0][1] += qv.x * kw.y;
            sacc[1][0] += qv.y * kw.x; sacc[1][1] += qv.y * kw.y;
            sacc[2][0] += qv.z * kw.x; sacc[2][1] += qv.z * kw.y;
            sacc[3][0] += qv.w * kw.x; sacc[3][1] += qv.w * kw.y;
        }
        // masked store of raw scores
#pragma unroll
        for (int a = 0; a < 4; ++a) {
            const int ig = q0 + sy * 4 + a;
#pragma unroll
            for (int cc = 0; cc < 2; ++cc) {
                const int jg = j0 + sx * 2 + cc;
                p_s[(sy * 4 + a) * PS_LD + sx * 2 + cc] =
                    (jg <= ig) ? sacc[a][cc] : -1e30f;
            }
        }
        __syncthreads();

        // ---- online-softmax row stats (wave 0, one lane per row) ----
        if (tid < BR) {
            const int r = tid;
            const float m_old = m_s[r];
            float mx = m_old;
            for (int j = 0; j < BC; ++j) mx = fmaxf(mx, p_s[r * PS_LD + j]);
            const float al = __expf(m_old - mx);
            float sum = 0.0f;
            for (int j = 0; j < BC; ++j) {
                const float pv = __expf(p_s[r * PS_LD + j] - mx);
                p_s[r * PS_LD + j] = pv;
                sum += pv;
            }
            m_s[r]  = mx;
            l_s[r]  = l_s[r] * al + sum;
            al_s[r] = al;
        }
        __syncthreads();

        // ---- rescale accumulators + stage V (reuses kv buffer) ----
        {
            const float al0 = al_s[g * 4 + 0];
            const float al1 = al_s[g * 4 + 1];
            const float al2 = al_s[g * 4 + 2];
            const float al3 = al_s[g * 4 + 3];
#pragma unroll
            for (int e = 0; e < 4; ++e) {
                acc[0][e] *= al0; acc[1][e] *= al1;
                acc[2][e] *= al2; acc[3][e] *= al3;
            }
        }
        for (int i = tid; i < BC * (D_ / 4); i += 256) {
            const int j  = i >> 5;
            const int c4 = i & 31;
            const float4 val =
                *(const float4*)(vbase + (size_t)(j0 + j) * (HKV_ * D_) + c4 * 4);
            *(float4*)&kv[j * VT_LD + c4 * 4] = val;
        }
        __syncthreads();

        // ---- PV accumulate ----
#pragma unroll 2
        for (int j = 0; j < BC; ++j) {
            const float4 vv = *(const float4*)&kv[j * VT_LD + c * 4];
            const float p0 = p_s[(g * 4 + 0) * PS_LD + j];
            const float p1 = p_s[(g * 4 + 1) * PS_LD + j];
            const float p2 = p_s[(g * 4 + 2) * PS_LD + j];
            const float p3 = p_s[(g * 4 + 3) * PS_LD + j];
            acc[0][0] += p0 * vv.x; acc[0][1] += p0 * vv.y;
            acc[0][2] += p0 * vv.z; acc[0][3] += p0 * vv.w;
            acc[1][0] += p1 * vv.x; acc[1][1] += p1 * vv.y;
            acc[1][2] += p1 * vv.z; acc[1][3] += p1 * vv.w;
            acc[2][0] += p2 * vv.x; acc[2][1] += p2 * vv.y;
            acc[2][2] += p2 * vv.z; acc[2][3] += p2 * vv.w;
            acc[3][0] += p3 * vv.x; acc[3][1] += p3 * vv.y;
            acc[3][2] += p3 * vv.z; acc[3][3] += p3 * vv.w;
        }
    }

    // ---- epilogue: divide by l, store ----
#pragma unroll
    for (int a = 0; a < 4; ++a) {
        const int r = g * 4 + a;
        const float inv = 1.0f / l_s[r];
        float4 o;
        o.x = acc[a][0] * inv; o.y = acc[a][1] * inv;
        o.z = acc[a][2] * inv; o.w = acc[a][3] * inv;
        *(float4*)(out + (((size_t)b * S_ + q0 + r) * H_ + h) * D_ + c * 4) = o;
    }
}

// ---------------------------------------------------------------------------
extern "C" void kernel_launch(void* const* d_in, const int* in_sizes, int n_in,
                              void* d_out, int out_size, void* d_ws,
                              size_t ws_size, hipStream_t stream) {
    const float* q    = (const float*)d_in[0];
    const float* k    = (const float*)d_in[1];
    const float* v    = (const float*)d_in[2];
    const float* kc   = (const float*)d_in[3];
    const float* vc   = (const float*)d_in[4];
    const int*   slot = (const int*)d_in[5];
    float* out = (float*)d_out;

    hipLaunchKernelGGL(copy_caches_kernel, dim3(1024), dim3(256), 0, stream,
                       kc, vc, out);
    hipLaunchKernelGGL(scatter_kernel, dim3(NSLOT), dim3(256), 0, stream,
                       k, v, slot, out);
    hipLaunchKernelGGL(attn_kernel, dim3(S_ / BR, B_ * H_), dim3(256), 0,
                       stream, q, k, v, out);
}

// Round 2
// 651.745 us; speedup vs baseline: 4.3242x; 4.3242x over previous
//
#include <hip/hip_runtime.h>
#include <math.h>

// Problem constants: B,S,H,HKV,D = 2,2048,32,8,128
#define B_    2
#define S_    2048
#define H_    32
#define HKV_  8
#define D_    128
#define REP_  (H_ / HKV_)                 // 4
#define SCALE 0.08838834764831845f        // 1/sqrt(128)

#define KV_ROW (HKV_ * D_)                // 1024 floats per cache row
#define NSLOT  (B_ * S_)                  // 4096
#define OUT_OFF_K ((size_t)B_ * S_ * H_ * D_)   // 16777216 floats

// MFMA flash tiling: 4 waves/block, each wave owns 16 Q rows -> BR=64, BC=64
#define BR 64
#define BC 64
#define QK_LD 136   // q/k LDS row stride in bf16 (128 + 8): rows 16B-aligned, 2-way-max conflicts
#define VT_LD 72    // v-transposed LDS row stride (64 + 8)
#define P_LD  72    // p LDS row stride

typedef __attribute__((ext_vector_type(8))) short bf16x8; // 8 bf16 = 4 VGPRs
typedef __attribute__((ext_vector_type(4))) float f32x4;  // C/D frag

static __device__ __forceinline__ short f2bf(float f) {
    unsigned u = __builtin_bit_cast(unsigned, f);
    u += 0x7fff + ((u >> 16) & 1);   // round-to-nearest-even
    return (short)(u >> 16);
}

// ---------------------------------------------------------------------------
__global__ void copy_caches_kernel(const float* __restrict__ kc,
                                   const float* __restrict__ vc,
                                   float* __restrict__ out) {
    const int n4 = NSLOT * KV_ROW / 4;
    float4* ok = (float4*)(out + OUT_OFF_K);
    float4* ov = (float4*)(out + OUT_OFF_K + (size_t)NSLOT * KV_ROW);
    const float4* ik = (const float4*)kc;
    const float4* iv = (const float4*)vc;
    for (int i = blockIdx.x * blockDim.x + threadIdx.x; i < n4;
         i += gridDim.x * blockDim.x) {
        ok[i] = ik[i];
        ov[i] = iv[i];
    }
}

__global__ void scatter_kernel(const float* __restrict__ k,
                               const float* __restrict__ v,
                               const int* __restrict__ slot,
                               float* __restrict__ out) {
    const int row = blockIdx.x;
    const int dst = slot[row];
    const float4* ks = (const float4*)(k + (size_t)row * KV_ROW);
    const float4* vs = (const float4*)(v + (size_t)row * KV_ROW);
    float4* kd = (float4*)(out + OUT_OFF_K + (size_t)dst * KV_ROW);
    float4* vd = (float4*)(out + OUT_OFF_K + (size_t)NSLOT * KV_ROW +
                           (size_t)dst * KV_ROW);
    const int t = threadIdx.x;
    kd[t] = ks[t];
    vd[t] = vs[t];
}

// ---------------------------------------------------------------------------
// Causal GQA flash attention with bf16 MFMA (16x16x32), fp32 accumulate.
// Grid: (S/BR, B*H). Block: 256 threads = 4 waves; wave w owns Q rows
// q0+16w .. q0+16w+15.
__global__ __launch_bounds__(256, 2) void attn_kernel(
    const float* __restrict__ q, const float* __restrict__ k,
    const float* __restrict__ v, float* __restrict__ out) {
    __shared__ short q_s[BR * QK_LD];        // 17408 B, scaled bf16, row-major
    __shared__ short k_s[BC * QK_LD];        // 17408 B, row-major
    __shared__ short vt_s[D_ * VT_LD];       // 18432 B, transposed [d][j]
    __shared__ short p_s[4 * 16 * P_LD];     //  9216 B, per-wave P regions

    const int qt   = blockIdx.x;
    const int bh   = blockIdx.y;
    const int b    = bh >> 5;          // / H_
    const int h    = bh & 31;
    const int hkv  = h >> 2;           // / REP_
    const int tid  = threadIdx.x;
    const int q0   = qt * BR;
    const int wave = tid >> 6;
    const int lane = tid & 63;
    const int n16  = lane & 15;        // C col / A row / B col index
    const int quad = lane >> 4;        // 0..3

    // ---- stage Q (bf16, pre-scaled) ----
    const float* qbase = q + (((size_t)b * S_ + q0) * H_ + h) * D_;
#pragma unroll
    for (int it = 0; it < 8; ++it) {
        const int i  = tid + it * 256;
        const int r  = i >> 5;         // 0..63
        const int c4 = i & 31;
        const float4 val = *(const float4*)(qbase + (size_t)r * (H_ * D_) + c4 * 4);
        short4 sv;
        sv.x = f2bf(val.x * SCALE); sv.y = f2bf(val.y * SCALE);
        sv.z = f2bf(val.z * SCALE); sv.w = f2bf(val.w * SCALE);
        *(short4*)&q_s[r * QK_LD + c4 * 4] = sv;
    }

    const float* kbase = k + ((size_t)b * S_ * HKV_ + hkv) * D_;
    const float* vbase = v + ((size_t)b * S_ * HKV_ + hkv) * D_;

    float m_r[4], l_r[4];
#pragma unroll
    for (int r = 0; r < 4; ++r) { m_r[r] = -1e30f; l_r[r] = 0.0f; }
    f32x4 acc[8];
#pragma unroll
    for (int dt = 0; dt < 8; ++dt) acc[dt] = (f32x4){0.f, 0.f, 0.f, 0.f};

    const int nkt = qt + 1;
    short* pw = p_s + wave * 16 * P_LD;

    for (int kt = 0; kt < nkt; ++kt) {
        const int j0 = kt * BC;
        __syncthreads();   // previous tile's MFMA reads of k_s/vt_s done
        // ---- stage K (bf16 row-major) ----
#pragma unroll
        for (int it = 0; it < 8; ++it) {
            const int i  = tid + it * 256;
            const int j  = i >> 5;
            const int c4 = i & 31;
            const float4 val =
                *(const float4*)(kbase + (size_t)(j0 + j) * KV_ROW + c4 * 4);
            short4 sv;
            sv.x = f2bf(val.x); sv.y = f2bf(val.y);
            sv.z = f2bf(val.z); sv.w = f2bf(val.w);
            *(short4*)&k_s[j * QK_LD + c4 * 4] = sv;
        }
        // ---- stage V transposed (bf16 [d][j]) ----
#pragma unroll
        for (int it = 0; it < 8; ++it) {
            const int i  = tid + it * 256;
            const int j  = i & 63;
            const int c4 = i >> 6;     // 0..31
            const float4 val =
                *(const float4*)(vbase + (size_t)(j0 + j) * KV_ROW + c4 * 4);
            const int d0 = c4 * 4;
            vt_s[(d0 + 0) * VT_LD + j] = f2bf(val.x);
            vt_s[(d0 + 1) * VT_LD + j] = f2bf(val.y);
            vt_s[(d0 + 2) * VT_LD + j] = f2bf(val.z);
            vt_s[(d0 + 3) * VT_LD + j] = f2bf(val.w);
        }
        __syncthreads();

        // ---- QK^T: wave's 16 rows x 64 cols, 4 col-tiles x 4 k-slices ----
        f32x4 sc[4];
#pragma unroll
        for (int t = 0; t < 4; ++t) sc[t] = (f32x4){0.f, 0.f, 0.f, 0.f};
#pragma unroll
        for (int ks = 0; ks < 4; ++ks) {
            const bf16x8 af =
                *(const bf16x8*)&q_s[(wave * 16 + n16) * QK_LD + ks * 32 + quad * 8];
#pragma unroll
            for (int t = 0; t < 4; ++t) {
                const bf16x8 bfr =
                    *(const bf16x8*)&k_s[(t * 16 + n16) * QK_LD + ks * 32 + quad * 8];
                sc[t] = __builtin_amdgcn_mfma_f32_16x16x32_bf16(af, bfr, sc[t], 0, 0, 0);
            }
        }

        // ---- online softmax, all in registers (row = quad*4+r per wave) ----
        const bool diag = (kt == nkt - 1);  // only tile where j0 == q0
        float alpha[4];
#pragma unroll
        for (int r = 0; r < 4; ++r) {
            const int igl = wave * 16 + quad * 4 + r;  // local row (q0==j0 on diag)
            float v0 = sc[0][r], v1 = sc[1][r], v2 = sc[2][r], v3 = sc[3][r];
            if (diag) {
                if (n16      > igl) v0 = -1e30f;
                if (16 + n16 > igl) v1 = -1e30f;
                if (32 + n16 > igl) v2 = -1e30f;
                if (48 + n16 > igl) v3 = -1e30f;
            }
            float mxr = fmaxf(fmaxf(v0, v1), fmaxf(v2, v3));
            mxr = fmaxf(mxr, __shfl_xor(mxr, 1));
            mxr = fmaxf(mxr, __shfl_xor(mxr, 2));
            mxr = fmaxf(mxr, __shfl_xor(mxr, 4));
            mxr = fmaxf(mxr, __shfl_xor(mxr, 8));
            const float mnew = fmaxf(m_r[r], mxr);
            alpha[r] = __expf(m_r[r] - mnew);
            m_r[r] = mnew;
            const float p0 = __expf(v0 - mnew);
            const float p1 = __expf(v1 - mnew);
            const float p2 = __expf(v2 - mnew);
            const float p3 = __expf(v3 - mnew);
            float s = p0 + p1 + p2 + p3;
            s += __shfl_xor(s, 1);
            s += __shfl_xor(s, 2);
            s += __shfl_xor(s, 4);
            s += __shfl_xor(s, 8);
            l_r[r] = l_r[r] * alpha[r] + s;
            // P -> LDS (bf16, A-layout source: row-major 16 x BC, own region)
            const int pr = (quad * 4 + r) * P_LD + n16;
            pw[pr]      = f2bf(p0);
            pw[pr + 16] = f2bf(p1);
            pw[pr + 32] = f2bf(p2);
            pw[pr + 48] = f2bf(p3);
        }
        // rescale O accumulators
#pragma unroll
        for (int dt = 0; dt < 8; ++dt)
#pragma unroll
            for (int r = 0; r < 4; ++r) acc[dt][r] *= alpha[r];

        // ---- PV: O(16x128) += P(16x64) * V(64x128) ----
#pragma unroll
        for (int ks = 0; ks < 2; ++ks) {
            const bf16x8 af = *(const bf16x8*)&pw[n16 * P_LD + ks * 32 + quad * 8];
#pragma unroll
            for (int dt = 0; dt < 8; ++dt) {
                const bf16x8 bfr =
                    *(const bf16x8*)&vt_s[(dt * 16 + n16) * VT_LD + ks * 32 + quad * 8];
                acc[dt] = __builtin_amdgcn_mfma_f32_16x16x32_bf16(af, bfr, acc[dt], 0, 0, 0);
            }
        }
    }

    // ---- epilogue ----
    float inv[4];
#pragma unroll
    for (int r = 0; r < 4; ++r) inv[r] = 1.0f / l_r[r];
    float* obase = out + (((size_t)b * S_ + q0 + wave * 16) * H_ + h) * D_;
#pragma unroll
    for (int dt = 0; dt < 8; ++dt)
#pragma unroll
        for (int r = 0; r < 4; ++r)
            obase[(size_t)(quad * 4 + r) * (H_ * D_) + dt * 16 + n16] =
                acc[dt][r] * inv[r];
}

// ---------------------------------------------------------------------------
extern "C" void kernel_launch(void* const* d_in, const int* in_sizes, int n_in,
                              void* d_out, int out_size, void* d_ws,
                              size_t ws_size, hipStream_t stream) {
    const float* q    = (const float*)d_in[0];
    const float* k    = (const float*)d_in[1];
    const float* v    = (const float*)d_in[2];
    const float* kc   = (const float*)d_in[3];
    const float* vc   = (const float*)d_in[4];
    const int*   slot = (const int*)d_in[5];
    float* out = (float*)d_out;

    hipLaunchKernelGGL(copy_caches_kernel, dim3(1024), dim3(256), 0, stream,
                       kc, vc, out);
    hipLaunchKernelGGL(scatter_kernel, dim3(NSLOT), dim3(256), 0, stream,
                       k, v, slot, out);
    hipLaunchKernelGGL(attn_kernel, dim3(S_ / BR, B_ * H_), dim3(256), 0,
                       stream, q, k, v, out);
}

// Round 4
// 344.807 us; speedup vs baseline: 8.1735x; 1.8902x over previous
//
#include <hip/hip_runtime.h>
#include <math.h>

// Problem constants: B,S,H,HKV,D = 2,2048,32,8,128
#define B_    2
#define S_    2048
#define H_    32
#define HKV_  8
#define D_    128
#define SCALE_LOG2E 0.12751743581f        // (1/sqrt(128)) * log2(e)

#define KV_ROW (HKV_ * D_)                // 1024 floats per cache row
#define NSLOT  (B_ * S_)                  // 4096
#define OUT_OFF_K ((size_t)B_ * S_ * H_ * D_)   // 16777216 floats
#define KV_ELEMS ((size_t)B_ * HKV_ * S_ * D_)  // 4194304 bf16 per ws tensor

// Flash tiling: 4 waves/block, each wave owns 32 q-rows -> BR=128, BC=64
#define BR 128
#define BC 64
#define NQT (S_ / BR)      // 16 q-tiles
#define K_LD 136           // k_s row stride (shorts): 272 B, 2-way max conflicts
#define V_LD 72            // vt_s row stride (shorts): 144 B
#define P_LD 72            // p_s row stride (shorts): 144 B (cols 64..71 = pad, reused for l)

typedef __attribute__((ext_vector_type(8)))  short bf16x8;  // 4 VGPRs
typedef __attribute__((ext_vector_type(16))) float f32x16;  // 32x32 C/D frag

static __device__ __forceinline__ short f2bf(float f) {
    unsigned u = __builtin_bit_cast(unsigned, f);
    u += 0x7fff + ((u >> 16) & 1);   // RNE
    return (short)(u >> 16);
}

// ---------------------------------------------------------------------------
__global__ void copy_caches_kernel(const float* __restrict__ kc,
                                   const float* __restrict__ vc,
                                   float* __restrict__ out) {
    const int n4 = NSLOT * KV_ROW / 4;
    float4* ok = (float4*)(out + OUT_OFF_K);
    float4* ov = (float4*)(out + OUT_OFF_K + (size_t)NSLOT * KV_ROW);
    const float4* ik = (const float4*)kc;
    const float4* iv = (const float4*)vc;
    for (int i = blockIdx.x * blockDim.x + threadIdx.x; i < n4;
         i += gridDim.x * blockDim.x) {
        ok[i] = ik[i];
        ov[i] = iv[i];
    }
}

// Fused: slot scatter (fp32 caches) + bf16 K ws (row-major) + bf16 V^T ws.
// Grid: (S/64, B*HKV), 256 threads.
__global__ void prep_kernel(const float* __restrict__ k,
                            const float* __restrict__ v,
                            const int* __restrict__ slot,
                            float* __restrict__ out,
                            short* __restrict__ kbw,
                            short* __restrict__ vtw) {
    const int b   = blockIdx.y >> 3;
    const int hkv = blockIdx.y & 7;
    const int s0  = blockIdx.x * 64;
    const int tid = threadIdx.x;

    float* outk = out + OUT_OFF_K;
    float* outv = outk + (size_t)NSLOT * KV_ROW;
    short* kb   = kbw + ((size_t)(b * HKV_ + hkv) * S_) * D_;
    short* vtb  = vtw + ((size_t)(b * HKV_ + hkv) * D_) * S_;

    // K: coalesced float4; scatter fp32 + bf16 ws (row-major)
#pragma unroll
    for (int it = 0; it < 8; ++it) {
        const int idx = it * 256 + tid;            // 64 rows x 32 float4
        const int j   = idx >> 5;
        const int c4  = idx & 31;
        const int s   = s0 + j;
        const int row = b * S_ + s;
        const float4 val =
            *(const float4*)(k + ((size_t)row * HKV_ + hkv) * D_ + c4 * 4);
        const int dst = slot[row];
        *(float4*)(outk + (size_t)dst * KV_ROW + hkv * D_ + c4 * 4) = val;
        short4 sv;
        sv.x = f2bf(val.x); sv.y = f2bf(val.y);
        sv.z = f2bf(val.z); sv.w = f2bf(val.w);
        *(short4*)(kb + (size_t)s * D_ + c4 * 4) = sv;
    }
    // V: scatter fp32 (coalesced)
#pragma unroll
    for (int it = 0; it < 8; ++it) {
        const int idx = it * 256 + tid;
        const int j   = idx >> 5;
        const int c4  = idx & 31;
        const int s   = s0 + j;
        const int row = b * S_ + s;
        const float4 val =
            *(const float4*)(v + ((size_t)row * HKV_ + hkv) * D_ + c4 * 4);
        const int dst = slot[row];
        *(float4*)(outv + (size_t)dst * KV_ROW + hkv * D_ + c4 * 4) = val;
    }
    // V^T ws: reads coalesced along d (L2-hot), writes 16B/lane scattered
    // (L2 absorbs; whole 128x64 region fully written).
#pragma unroll
    for (int it = 0; it < 4; ++it) {
        const int idx = it * 256 + tid;            // 128 d x 8 j-chunks
        const int d   = idx & 127;
        const int c8  = idx >> 7;
        short vv[8];
#pragma unroll
        for (int jj = 0; jj < 8; ++jj) {
            const int s = s0 + c8 * 8 + jj;
            vv[jj] = f2bf(v[((size_t)(b * S_ + s) * HKV_ + hkv) * D_ + d]);
        }
        *(bf16x8*)(vtb + (size_t)d * S_ + s0 + c8 * 8) = *(bf16x8*)vv;
    }
}

// ---------------------------------------------------------------------------
// Causal GQA flash attention. 32x32x16 bf16 MFMA computing S^T = K*Q^T.
// Grid: (NQT/2, B*H) with causal pairing (qt, 15-qt). 256 thr = 4 waves,
// wave w owns q-rows [q0+32w, q0+32w+32).
__global__ __launch_bounds__(256, 3) void attn_kernel(
    const float* __restrict__ q, const short* __restrict__ kbw,
    const short* __restrict__ vtw, float* __restrict__ out) {
    __shared__ short k_s[BC * K_LD];       // 17408 B
    __shared__ short vt_s[D_ * V_LD];      // 18432 B
    __shared__ short p_s[4 * 32 * P_LD];   // 18432 B  (total 53.0 KB)

    const int bh   = blockIdx.y;
    const int b    = bh >> 5;
    const int h    = bh & 31;
    const int hkv  = h >> 2;
    const int tid  = threadIdx.x;
    const int wave = tid >> 6;
    const int lane = tid & 63;
    const int n32  = lane & 31;
    const int sig  = lane >> 5;

    const short* kbb  = kbw + ((size_t)(b * HKV_ + hkv) * S_) * D_;
    const short* vtbb = vtw + ((size_t)(b * HKV_ + hkv) * D_) * S_;
    short* pw = p_s + wave * 32 * P_LD;

#pragma unroll 1
    for (int pi = 0; pi < 2; ++pi) {
        const int qt = pi ? (NQT - 1 - blockIdx.x) : blockIdx.x;
        const int q0 = qt * BR;
        const int r0 = q0 + wave * 32;          // wave's first q-row

        // ---- cache Q B-fragments (scaled into log2 domain) ----
        const float* qrow =
            q + (((size_t)(b * S_ + r0 + n32)) * H_ + h) * D_ + sig * 8;
        bf16x8 qf[8];
#pragma unroll
        for (int ks = 0; ks < 8; ++ks) {
            const float4 a = *(const float4*)(qrow + ks * 16);
            const float4 c = *(const float4*)(qrow + ks * 16 + 4);
            short t[8];
            t[0] = f2bf(a.x * SCALE_LOG2E); t[1] = f2bf(a.y * SCALE_LOG2E);
            t[2] = f2bf(a.z * SCALE_LOG2E); t[3] = f2bf(a.w * SCALE_LOG2E);
            t[4] = f2bf(c.x * SCALE_LOG2E); t[5] = f2bf(c.y * SCALE_LOG2E);
            t[6] = f2bf(c.z * SCALE_LOG2E); t[7] = f2bf(c.w * SCALE_LOG2E);
            qf[ks] = *(bf16x8*)t;
        }

        f32x16 acc[4];
#pragma unroll
        for (int dt = 0; dt < 4; ++dt)
#pragma unroll
            for (int e = 0; e < 16; ++e) acc[dt][e] = 0.0f;
        float l_lane = 0.0f;

        const int nkt = 2 * qt + 2;
        for (int kt = 0; kt < nkt; ++kt) {
            const int j0 = kt * BC;
            __syncthreads();
            // ---- stage K tile (bf16 row-major, 16 KB) ----
#pragma unroll
            for (int it = 0; it < 4; ++it) {
                const int idx = it * 256 + tid;    // 64 rows x 16 chunks
                const int j   = idx >> 4;
                const int c16 = idx & 15;
                *(uint4*)&k_s[j * K_LD + c16 * 8] =
                    *(const uint4*)(kbb + (size_t)(j0 + j) * D_ + c16 * 8);
            }
            // ---- stage V^T tile (bf16, 16 KB) ----
#pragma unroll
            for (int it = 0; it < 4; ++it) {
                const int idx = it * 256 + tid;    // 128 d x 8 chunks
                const int d   = idx >> 3;
                const int c8  = idx & 7;
                *(uint4*)&vt_s[d * V_LD + c8 * 8] =
                    *(const uint4*)(vtbb + (size_t)d * S_ + j0 + c8 * 8);
            }
            __syncthreads();

            if (j0 >= r0 + 32) continue;           // wave fully masked
            const bool diag = (j0 + 63 > r0);

            // ---- S^T = K * Q^T, softmax, pack P ----
#pragma unroll
            for (int jt = 0; jt < 2; ++jt) {
                f32x16 sc;
#pragma unroll
                for (int e = 0; e < 16; ++e) sc[e] = 0.0f;
#pragma unroll
                for (int ks = 0; ks < 8; ++ks) {
                    const bf16x8 af = *(const bf16x8*)
                        &k_s[(jt * 32 + n32) * K_LD + ks * 16 + sig * 8];
                    sc = __builtin_amdgcn_mfma_f32_32x32x16_bf16(af, qf[ks],
                                                                 sc, 0, 0, 0);
                }
                const int ig = r0 + n32;
#pragma unroll
                for (int qq = 0; qq < 4; ++qq) {
                    float p[4];
#pragma unroll
                    for (int r = 0; r < 4; ++r) {
                        const int jg = j0 + jt * 32 + r + 8 * qq + 4 * sig;
                        const float s = sc[qq * 4 + r];
                        float pv = __builtin_amdgcn_exp2f(s);
                        if (diag && jg > ig) pv = 0.0f;
                        p[r] = pv;
                        l_lane += pv;
                    }
                    const unsigned u0 = __builtin_amdgcn_perm(
                        __builtin_bit_cast(unsigned, p[1]),
                        __builtin_bit_cast(unsigned, p[0]), 0x07060302u);
                    const unsigned u1 = __builtin_amdgcn_perm(
                        __builtin_bit_cast(unsigned, p[3]),
                        __builtin_bit_cast(unsigned, p[2]), 0x07060302u);
                    uint2 pr; pr.x = u0; pr.y = u1;
                    *(uint2*)&pw[n32 * P_LD + jt * 32 + qq * 8 + sig * 4] = pr;
                }
            }

            // ---- O += P * V ----
#pragma unroll
            for (int ks = 0; ks < 4; ++ks) {
                const bf16x8 ap =
                    *(const bf16x8*)&pw[n32 * P_LD + ks * 16 + sig * 8];
#pragma unroll
                for (int dt = 0; dt < 4; ++dt) {
                    const bf16x8 bv = *(const bf16x8*)
                        &vt_s[(dt * 32 + n32) * V_LD + ks * 16 + sig * 8];
                    acc[dt] = __builtin_amdgcn_mfma_f32_32x32x16_bf16(
                        ap, bv, acc[dt], 0, 0, 0);
                }
            }
        }

        // ---- epilogue: l via p_s pad (lane pair i, i+32), store ----
        *(float*)(pw + n32 * P_LD + 64 + 2 * sig) = l_lane;
        __builtin_amdgcn_s_waitcnt(0);  // ds_write visible within wave
        float* ob = out + (((size_t)(b * S_ + r0)) * H_ + h) * D_;
#pragma unroll
        for (int r = 0; r < 16; ++r) {
            const int il = (r & 3) + 8 * (r >> 2) + 4 * sig;
            const float lt = *(float*)(pw + il * P_LD + 64) +
                             *(float*)(pw + il * P_LD + 66);
            const float inv = __builtin_amdgcn_rcpf(lt);
#pragma unroll
            for (int dt = 0; dt < 4; ++dt)
                ob[(size_t)il * (H_ * D_) + dt * 32 + n32] = acc[dt][r] * inv;
        }
    }
}

// ---------------------------------------------------------------------------
extern "C" void kernel_launch(void* const* d_in, const int* in_sizes, int n_in,
                              void* d_out, int out_size, void* d_ws,
                              size_t ws_size, hipStream_t stream) {
    const float* q    = (const float*)d_in[0];
    const float* k    = (const float*)d_in[1];
    const float* v    = (const float*)d_in[2];
    const float* kc   = (const float*)d_in[3];
    const float* vc   = (const float*)d_in[4];
    const int*   slot = (const int*)d_in[5];
    float* out = (float*)d_out;
    short* kbw = (short*)d_ws;                 // bf16 K  [B][HKV][S][D]
    short* vtw = kbw + KV_ELEMS;               // bf16 V^T [B][HKV][D][S]

    hipLaunchKernelGGL(copy_caches_kernel, dim3(1024), dim3(256), 0, stream,
                       kc, vc, out);
    hipLaunchKernelGGL(prep_kernel, dim3(S_ / 64, B_ * HKV_), dim3(256), 0,
                       stream, k, v, slot, out, kbw, vtw);
    hipLaunchKernelGGL(attn_kernel, dim3(NQT / 2, B_ * H_), dim3(256), 0,
                       stream, q, kbw, vtw, out);
}